// Round 1
// baseline (651.187 us; speedup 1.0000x reference)
//
#include <hip/hip_runtime.h>

#define N_ROWS 262144
#define DIM 64
#define NEMB 512

// fp64 exact score for near-tie refinement: ||w_k||^2 - 2 z.w_k
__device__ double score64(const float* zr, const float* __restrict__ w, int k) {
    const float* wk = w + k * DIM;
    double dot = 0.0, ws = 0.0;
#pragma unroll
    for (int d = 0; d < DIM; ++d) {
        double wv = (double)wk[d];
        dot = fma(wv, (double)zr[d], dot);
        ws  = fma(wv, wv, ws);
    }
    return ws - 2.0 * dot;
}

// Pass 1: per-row argmin over 512 codewords + loss partial per block + idx out.
__global__ __launch_bounds__(256) void vq_pass1(
    const float* __restrict__ z, const float* __restrict__ w,
    int* __restrict__ idx, float* __restrict__ partials)
{
    __shared__ float wsq_s[NEMB];
    __shared__ float red_s[4];

    // cooperative ||w_k||^2
    for (int k = threadIdx.x; k < NEMB; k += 256) {
        const float* wk = w + k * DIM;
        float a0 = 0.f, a1 = 0.f, a2 = 0.f, a3 = 0.f;
#pragma unroll
        for (int d = 0; d < DIM; d += 4) {
            a0 = fmaf(wk[d + 0], wk[d + 0], a0);
            a1 = fmaf(wk[d + 1], wk[d + 1], a1);
            a2 = fmaf(wk[d + 2], wk[d + 2], a2);
            a3 = fmaf(wk[d + 3], wk[d + 3], a3);
        }
        wsq_s[k] = (a0 + a1) + (a2 + a3);
    }
    __syncthreads();

    const int row = blockIdx.x * 256 + threadIdx.x;

    // z row -> 64 VGPRs (16x float4)
    float zr[DIM];
    const float4* zp = reinterpret_cast<const float4*>(z + (size_t)row * DIM);
#pragma unroll
    for (int i = 0; i < DIM / 4; ++i) {
        float4 v = zp[i];
        zr[4 * i + 0] = v.x; zr[4 * i + 1] = v.y;
        zr[4 * i + 2] = v.z; zr[4 * i + 3] = v.w;
    }

    // ||z||^2 (for the loss identity)
    float q0 = 0.f, q1 = 0.f, q2 = 0.f, q3 = 0.f;
#pragma unroll
    for (int d = 0; d < DIM; d += 4) {
        q0 = fmaf(zr[d + 0], zr[d + 0], q0);
        q1 = fmaf(zr[d + 1], zr[d + 1], q1);
        q2 = fmaf(zr[d + 2], zr[d + 2], q2);
        q3 = fmaf(zr[d + 3], zr[d + 3], q3);
    }
    const float zsq = (q0 + q1) + (q2 + q3);

    float best = 3.0e38f, second = 3.0e38f;
    int bi = 0, bi2 = 0;

    for (int k = 0; k < NEMB; ++k) {
        const float* wk = w + k * DIM;   // uniform address -> s_load broadcast
        float a0 = 0.f, a1 = 0.f, a2 = 0.f, a3 = 0.f;
#pragma unroll
        for (int d = 0; d < DIM; d += 4) {
            a0 = fmaf(wk[d + 0], zr[d + 0], a0);
            a1 = fmaf(wk[d + 1], zr[d + 1], a1);
            a2 = fmaf(wk[d + 2], zr[d + 2], a2);
            a3 = fmaf(wk[d + 3], zr[d + 3], a3);
        }
        float s = fmaf(-2.0f, (a0 + a1) + (a2 + a3), wsq_s[k]);
        if (s < best) {
            second = best; bi2 = bi;
            best = s; bi = k;
        } else if (s < second) {
            second = s; bi2 = k;
        }
    }

    // near-tie: re-rank top-2 in fp64 (rare, ~0.4% of rows)
    if (second - best < 1e-5f) {
        double s1 = score64(zr, w, bi);
        double s2 = score64(zr, w, bi2);
        if (s2 < s1 || (s2 == s1 && bi2 < bi)) { best = (float)s2; bi = bi2; }
        else                                   { best = (float)s1; }
    }

    idx[row] = bi;

    // loss partial: ||z - zq||^2 = ||z||^2 + (||zq||^2 - 2 z.zq) = zsq + best
    float v = zsq + best;
#pragma unroll
    for (int off = 32; off > 0; off >>= 1) v += __shfl_xor(v, off, 64);
    if ((threadIdx.x & 63) == 0) red_s[threadIdx.x >> 6] = v;
    __syncthreads();
    if (threadIdx.x == 0)
        partials[blockIdx.x] = (red_s[0] + red_s[1]) + (red_s[2] + red_s[3]);
}

// Pass 2: coalesced gather out[n][d] = w[idx[n]][d], float4-wide.
__global__ __launch_bounds__(256) void vq_gather(
    const float* __restrict__ w, const int* __restrict__ idx,
    float* __restrict__ out)
{
    const int total = N_ROWS * DIM / 4;          // 4194304 float4s
    const float4* w4 = reinterpret_cast<const float4*>(w);
    float4* o4 = reinterpret_cast<float4*>(out);
    for (int e = blockIdx.x * 256 + threadIdx.x; e < total; e += 4096 * 256) {
        int n = e >> 4;
        int j = e & 15;
        o4[e] = w4[idx[n] * 16 + j];
    }
}

// Pass 3: reduce 1024 block partials -> vq_loss scalar at out[N*D].
__global__ __launch_bounds__(256) void vq_final(
    const float* __restrict__ partials, float* __restrict__ out)
{
    __shared__ float sh[4];
    float v = 0.f;
    for (int i = threadIdx.x; i < 1024; i += 256) v += partials[i];
#pragma unroll
    for (int off = 32; off > 0; off >>= 1) v += __shfl_xor(v, off, 64);
    if ((threadIdx.x & 63) == 0) sh[threadIdx.x >> 6] = v;
    __syncthreads();
    if (threadIdx.x == 0) {
        double s = (double)((sh[0] + sh[1]) + (sh[2] + sh[3]));
        // vq_loss = (1 + 0.1) * mean
        out[(size_t)N_ROWS * DIM] = (float)(s * 1.1 / (double)((size_t)N_ROWS * DIM));
    }
}

extern "C" void kernel_launch(void* const* d_in, const int* in_sizes, int n_in,
                              void* d_out, int out_size, void* d_ws, size_t ws_size,
                              hipStream_t stream) {
    const float* z = (const float*)d_in[0];   // [1, 262144, 64] fp32
    const float* w = (const float*)d_in[1];   // [512, 64] fp32
    float* out = (float*)d_out;               // 262144*64 + 1 fp32

    float* partials = (float*)d_ws;                   // 1024 floats
    int* idx = (int*)((char*)d_ws + 4096);            // 262144 ints

    vq_pass1<<<N_ROWS / 256, 256, 0, stream>>>(z, w, idx, partials);
    vq_gather<<<4096, 256, 0, stream>>>(w, idx, out);
    vq_final<<<1, 256, 0, stream>>>(partials, out);
}

// Round 2
// 78.943 us; speedup vs baseline: 8.2488x; 8.2488x over previous
//
#include <hip/hip_runtime.h>

#define N_ROWS 262144
#define DIM 64
#define NEMB 512

typedef __attribute__((ext_vector_type(8))) short bf16x8;
typedef __attribute__((ext_vector_type(4))) float f32x4;
typedef __attribute__((ext_vector_type(4))) int i32x4;

__device__ inline unsigned short f2bf_rne(float x) {
    unsigned u = __float_as_uint(x);
    unsigned r = u + 0x7fffu + ((u >> 16) & 1u);
    return (unsigned short)(r >> 16);
}
__device__ inline float bf2f(unsigned short h) {
    return __uint_as_float(((unsigned)h) << 16);
}

// Prep: w2 = -2*w split into bf16 hi/lo, plus wsq = ||w_k||^2 (fp32).
__global__ __launch_bounds__(256) void vq_prep(
    const float* __restrict__ w, float* __restrict__ wsq,
    short* __restrict__ w2h, short* __restrict__ w2l)
{
    int row = blockIdx.x * 256 + threadIdx.x;
    if (row >= NEMB) return;
    const float* wr = w + row * DIM;
    float s = 0.f;
#pragma unroll 8
    for (int d = 0; d < DIM; ++d) {
        float v = wr[d];
        s = fmaf(v, v, s);
        float m2 = -2.0f * v;
        unsigned short h = f2bf_rne(m2);
        float rest = m2 - bf2f(h);
        w2h[row * DIM + d] = (short)h;
        w2l[row * DIM + d] = (short)f2bf_rne(rest);
    }
    wsq[row] = s;
}

// Main: per wave 128 rows (2 iters x 4 row-groups x 16). A = w-tile (LDS hi,
// L2 lo), B = z rows (VGPR frags). acc init = wsq -> acc = wsq - 2 z.w.
// C/D layout (m89): m(codeword) = 4*(lane>>4)+reg, n(z-row) = lane&15.
__global__ __launch_bounds__(512) void vq_main(
    const float* __restrict__ z, const float* __restrict__ wsq,
    const short* __restrict__ w2h, const short* __restrict__ w2l,
    int* __restrict__ idx, float* __restrict__ partials)
{
    __shared__ short lds[NEMB * DIM];  // 64 KiB, XOR-swizzled w2h

    const int tid = threadIdx.x;

    // stage w2h -> LDS; swizzle byte_off ^= (row&7)<<4 (T2: break 128B-row bank aliasing)
#pragma unroll
    for (int i = 0; i < 8; ++i) {
        int c = i * 512 + tid;               // 16B chunk id, 4096 total
        int row = c >> 3;
        int off = (c & 7) << 4;
        int swz = off ^ ((row & 7) << 4);
        i32x4 v = ((const i32x4*)w2h)[c];
        *(i32x4*)((char*)lds + row * 128 + swz) = v;
    }
    __syncthreads();

    const int lane = tid & 63;
    const int wv = tid >> 6;   // wave 0..7
    const int g = lane >> 4;   // 0..3
    const int ln = lane & 15;

    float loss_acc = 0.f;

    for (int it = 0; it < 2; ++it) {
        const int rb = blockIdx.x * 1024 + wv * 128 + it * 64;

        // ---- load + split z rows into B-frags (held across the k-loop) ----
        bf16x8 zh[4][2], zl[4][2];
        float zsq[4];
#pragma unroll
        for (int rg = 0; rg < 4; ++rg) {
            const float* zr = z + (size_t)(rb + rg * 16 + ln) * DIM + g * 8;
            float q = 0.f;
#pragma unroll
            for (int ks = 0; ks < 2; ++ks) {
                f32x4 a = *(const f32x4*)(zr + ks * 32);
                f32x4 b = *(const f32x4*)(zr + ks * 32 + 4);
                bf16x8 h, l;
#pragma unroll
                for (int j = 0; j < 8; ++j) {
                    float x = (j < 4) ? a[j] : b[j - 4];
                    q = fmaf(x, x, q);
                    unsigned short hb = f2bf_rne(x);
                    float rest = x - bf2f(hb);   // exact (Sterbenz)
                    h[j] = (short)hb;
                    l[j] = (short)f2bf_rne(rest);
                }
                zh[rg][ks] = h;
                zl[rg][ks] = l;
            }
            q += __shfl_xor(q, 16, 64);
            q += __shfl_xor(q, 32, 64);
            zsq[rg] = q;                 // full ||z_row||^2, row = rb+rg*16+ln
        }

        float best[4];
        int bi[4];
#pragma unroll
        for (int rg = 0; rg < 4; ++rg) { best[rg] = 3.0e38f; bi[rg] = 0; }

        // ---- k-tile loop: 32 tiles of 16 codewords ----
        for (int tile = 0; tile < 32; ++tile) {
            const int cb_base = tile * 16 + g * 4;
            const f32x4 wsqv = *(const f32x4*)(wsq + cb_base);

            const int arow = tile * 16 + ln;
            bf16x8 Ah[2], Al[2];
#pragma unroll
            for (int ks = 0; ks < 2; ++ks) {
                int off = ks * 64 + g * 16;
                Ah[ks] = *(const bf16x8*)((const char*)lds +
                          arow * 128 + (off ^ ((arow & 7) << 4)));
                Al[ks] = *(const bf16x8*)(w2l + arow * DIM + ks * 32 + g * 8);
            }

            f32x4 acc[4];
#pragma unroll
            for (int rg = 0; rg < 4; ++rg) acc[rg] = wsqv;

#pragma unroll
            for (int ks = 0; ks < 2; ++ks) {
#pragma unroll
                for (int rg = 0; rg < 4; ++rg)
                    acc[rg] = __builtin_amdgcn_mfma_f32_16x16x32_bf16(
                        Ah[ks], zh[rg][ks], acc[rg], 0, 0, 0);
#pragma unroll
                for (int rg = 0; rg < 4; ++rg)
                    acc[rg] = __builtin_amdgcn_mfma_f32_16x16x32_bf16(
                        Ah[ks], zl[rg][ks], acc[rg], 0, 0, 0);
#pragma unroll
                for (int rg = 0; rg < 4; ++rg)
                    acc[rg] = __builtin_amdgcn_mfma_f32_16x16x32_bf16(
                        Al[ks], zh[rg][ks], acc[rg], 0, 0, 0);
            }

#pragma unroll
            for (int rg = 0; rg < 4; ++rg) {
#pragma unroll
                for (int r = 0; r < 4; ++r) {
                    float s = acc[rg][r];
                    bool lt = s < best[rg];
                    bi[rg] = lt ? (cb_base + r) : bi[rg];
                    best[rg] = lt ? s : best[rg];
                }
            }
        }

        // ---- merge argmin across the 4 lane-groups; emit idx + loss ----
#pragma unroll
        for (int rg = 0; rg < 4; ++rg) {
            float b = best[rg];
            int i0 = bi[rg];
#pragma unroll
            for (int m = 16; m <= 32; m <<= 1) {
                float b2 = __shfl_xor(b, m, 64);
                int i2 = __shfl_xor(i0, m, 64);
                bool take = (b2 < b) || (b2 == b && i2 < i0);
                b = take ? b2 : b;
                i0 = take ? i2 : i0;
            }
            if (g == 0) idx[rb + rg * 16 + ln] = i0;
            loss_acc += zsq[rg] + b;   // every row counted 4x (per g) -> /4 at end
        }
    }

#pragma unroll
    for (int m = 1; m < 64; m <<= 1) loss_acc += __shfl_xor(loss_acc, m, 64);
    if (lane == 0) partials[blockIdx.x * 8 + wv] = loss_acc;
}

// Gather: out[n][d] = w[idx[n]][d], float4-coalesced.
__global__ __launch_bounds__(256) void vq_gather(
    const float* __restrict__ w, const int* __restrict__ idx,
    float* __restrict__ out)
{
    const int total = N_ROWS * DIM / 4;
    const float4* w4 = reinterpret_cast<const float4*>(w);
    float4* o4 = reinterpret_cast<float4*>(out);
    for (int e = blockIdx.x * 256 + threadIdx.x; e < total; e += 4096 * 256) {
        int n = e >> 4;
        int j = e & 15;
        o4[e] = w4[idx[n] * 16 + j];
    }
}

// Final: reduce 2048 wave partials -> loss scalar.
__global__ __launch_bounds__(256) void vq_final(
    const float* __restrict__ partials, float* __restrict__ out)
{
    __shared__ double sh[4];
    double v = 0.0;
    for (int i = threadIdx.x; i < 2048; i += 256) v += (double)partials[i];
#pragma unroll
    for (int m = 1; m < 64; m <<= 1) v += __shfl_xor(v, m, 64);
    if ((threadIdx.x & 63) == 0) sh[threadIdx.x >> 6] = v;
    __syncthreads();
    if (threadIdx.x == 0) {
        double s = sh[0] + sh[1] + sh[2] + sh[3];
        out[(size_t)N_ROWS * DIM] =
            (float)(s * 1.1 / (4.0 * (double)N_ROWS * (double)DIM));
    }
}

extern "C" void kernel_launch(void* const* d_in, const int* in_sizes, int n_in,
                              void* d_out, int out_size, void* d_ws, size_t ws_size,
                              hipStream_t stream) {
    const float* z = (const float*)d_in[0];   // [1, 262144, 64] fp32
    const float* w = (const float*)d_in[1];   // [512, 64] fp32
    float* out = (float*)d_out;               // 262144*64 + 1 fp32

    // workspace layout (16B-aligned)
    float* partials = (float*)d_ws;                            // 2048 f32
    float* wsq = (float*)((char*)d_ws + 8192);                 // 512 f32
    short* w2h = (short*)((char*)d_ws + 10240);                // 32768 bf16
    short* w2l = (short*)((char*)d_ws + 75776);                // 32768 bf16
    int* idx = (int*)((char*)d_ws + 140288);                   // 262144 i32

    vq_prep<<<2, 256, 0, stream>>>(w, wsq, w2h, w2l);
    vq_main<<<256, 512, 0, stream>>>(z, wsq, w2h, w2l, idx, partials);
    vq_gather<<<4096, 256, 0, stream>>>(w, idx, out);
    vq_final<<<1, 256, 0, stream>>>(partials, out);
}